// Round 2
// baseline (215.320 us; speedup 1.0000x reference)
//
#include <hip/hip_runtime.h>
#include <hip/hip_fp16.h>
#include <math.h>

#define N_NODES 100000
#define N_EDGES 1600000
#define IN_F    128
#define OUT_F   64
#define K_BKT     196                            // dst buckets of 512 nodes
#define BKT_SHIFT 9
#define BKT_NODES 512
#define BKT_CAP   10240                          // slots per bucket (E=8192, +22 sigma)
#define CHUNK     4096                           // partition block edge count
#define PBLKS     ((N_EDGES + CHUNK - 1) / CHUNK)          // 391
#define LTILES    (N_NODES / 16)                 // 6250 exact 16-row MFMA tiles
#define LBLKS     ((LTILES + 3) / 4)             // 1563 (4 waves/block)

typedef _Float16 half8 __attribute__((ext_vector_type(8)));
typedef _Float16 half4v __attribute__((ext_vector_type(4)));
typedef float    f32x4 __attribute__((ext_vector_type(4)));

// ---------------- workspace layout (4-byte units) ----------------
// fth      : N_NODES*OUT_F/2       (fp16 projected features, 12.8 MB)
// staging  : K_BKT*BKT_CAP uint    (packed src|dloc<<17, capacity layout, 8 MB)
// edge_src : K_BKT*BKT_CAP int     (CSR src ids, capacity layout, 8 MB)
// bcursor  : K_BKT                 (zero-init; after partition = bucket count)
// row_beg/row_end : N_NODES each

// blocks [0,PBLKS): in-LDS counting sort of a 4096-edge chunk into bucket
// regions at b*BKT_CAP (reservation atomics on 196 spread counters).
// blocks [PBLKS,..): MFMA fp16 linear — wave = 16-row tile of ft = feat @ W.
__global__ __launch_bounds__(256) void partition_linear_kernel(const int* __restrict__ src,
                                                               const int* __restrict__ dst,
                                                               int* __restrict__ bcursor,
                                                               unsigned* __restrict__ staging,
                                                               const float* __restrict__ feat,
                                                               const float* __restrict__ W,
                                                               __half* __restrict__ fth) {
    __shared__ int hist[256], lbase[256], gbase[256], sc[256];
    __shared__ unsigned sval[CHUNK];
    __shared__ int spos[CHUNK];
    int t = threadIdx.x;
    if (blockIdx.x < PBLKS) {
        hist[t] = 0;
        __syncthreads();
        int beg = blockIdx.x * CHUNK;
        int end = min(beg + CHUNK, N_EDGES);
        for (int i = beg + t; i < end; i += 256)
            atomicAdd(&hist[dst[i] >> BKT_SHIFT], 1);
        __syncthreads();
        int v = hist[t];
        sc[t] = v;
        __syncthreads();
        for (int off = 1; off < 256; off <<= 1) {
            int add = (t >= off) ? sc[t - off] : 0;
            __syncthreads();
            sc[t] += add;
            __syncthreads();
        }
        lbase[t] = sc[t] - v;                    // block-local exclusive
        if (t < K_BKT && v) gbase[t] = t * BKT_CAP + atomicAdd(&bcursor[t], v);
        hist[t] = 0;                             // reuse as rank counter
        __syncthreads();
        for (int i = beg + t; i < end; i += 256) {
            int s = src[i], d = dst[i];
            int b = d >> BKT_SHIFT;
            int r = atomicAdd(&hist[b], 1);
            int lp = lbase[b] + r;
            sval[lp] = (unsigned)s | ((unsigned)(d & (BKT_NODES - 1)) << 17);
            spos[lp] = gbase[b] + r;
        }
        __syncthreads();
        int n = end - beg;
        for (int p = t; p < n; p += 256) staging[spos[p]] = sval[p];
        return;
    }
    // ---- MFMA linear: one wave per 16-row tile ----
    int gwave = (blockIdx.x - PBLKS) * 4 + (t >> 6);
    if (gwave >= LTILES) return;
    int lane = t & 63;
    int m = lane & 15, kg = lane >> 4;
    int r0 = gwave * 16;

    // B fragments: B[k][n], n = lane&15, k = kb*32 + kg*8 + j  (W 32 KB, hot)
    half8 fb[4][4];
#pragma unroll
    for (int kb = 0; kb < 4; ++kb)
#pragma unroll
        for (int nb = 0; nb < 4; ++nb) {
            const float* wp = W + (size_t)(kb * 32 + kg * 8) * OUT_F + nb * 16 + m;
#pragma unroll
            for (int j = 0; j < 8; ++j)
                fb[kb][nb][j] = (_Float16)wp[j * OUT_F];
        }

    f32x4 acc[4];
#pragma unroll
    for (int nb = 0; nb < 4; ++nb) acc[nb] = (f32x4){0.f, 0.f, 0.f, 0.f};

#pragma unroll
    for (int kb = 0; kb < 4; ++kb) {
        const float4* ap = (const float4*)(feat + (size_t)(r0 + m) * IN_F + kb * 32 + kg * 8);
        float4 a0 = ap[0], a1 = ap[1];
        half8 fa = {(_Float16)a0.x, (_Float16)a0.y, (_Float16)a0.z, (_Float16)a0.w,
                    (_Float16)a1.x, (_Float16)a1.y, (_Float16)a1.z, (_Float16)a1.w};
#pragma unroll
        for (int nb = 0; nb < 4; ++nb)
            acc[nb] = __builtin_amdgcn_mfma_f32_16x16x32_f16(fa, fb[kb][nb], acc[nb], 0, 0, 0);
    }
    // D: col = lane&15, row = (lane>>4)*4 + i
#pragma unroll
    for (int nb = 0; nb < 4; ++nb)
#pragma unroll
        for (int i = 0; i < 4; ++i)
            fth[(size_t)(r0 + kg * 4 + i) * OUT_F + nb * 16 + m] = __float2half_rn(acc[nb][i]);
}

// one block per bucket: per-node counts + scan -> row_beg/row_end, then place
// src ids into exact CSR slots (capacity layout). One block -> full lines.
__global__ __launch_bounds__(256) void place_kernel(const unsigned* __restrict__ staging,
                                                    const int* __restrict__ bcursor,
                                                    int* __restrict__ row_beg,
                                                    int* __restrict__ row_end,
                                                    int* __restrict__ edge_src) {
    __shared__ int cnt[BKT_NODES], sc[256], lcur[BKT_NODES];
    int t = threadIdx.x;
    cnt[t] = 0; cnt[t + 256] = 0;
    __syncthreads();
    int base = blockIdx.x * BKT_CAP;
    int n = bcursor[blockIdx.x];
    for (int i = t; i < n; i += 256)
        atomicAdd(&cnt[staging[base + i] >> 17], 1);
    __syncthreads();
    int v0 = cnt[2 * t], v1 = cnt[2 * t + 1];
    int ts = v0 + v1;
    sc[t] = ts;
    __syncthreads();
    for (int off = 1; off < 256; off <<= 1) {
        int add = (t >= off) ? sc[t - off] : 0;
        __syncthreads();
        sc[t] += add;
        __syncthreads();
    }
    int excl = sc[t] - ts;
    int node0 = blockIdx.x * BKT_NODES;
    int b0 = base + excl, b1 = base + excl + v0;
    lcur[2 * t]     = b0;
    lcur[2 * t + 1] = b1;
    if (node0 + 2 * t < N_NODES)     { row_beg[node0 + 2 * t] = b0;     row_end[node0 + 2 * t] = b0 + v0; }
    if (node0 + 2 * t + 1 < N_NODES) { row_beg[node0 + 2 * t + 1] = b1; row_end[node0 + 2 * t + 1] = b1 + v1; }
    __syncthreads();
    for (int i = base + t; i < base + n; i += 256) {
        unsigned u = staging[i];
        int pos = atomicAdd(&lcur[u >> 17], 1);
        edge_src[pos] = (int)(u & 0x1FFFFu);
    }
}

// One wave per dst node, flash-attention style over 16-edge K/V tiles.
// Score: S(16 edges) = E(16x64) . d via 2x mfma_f32_16x16x32_f16
//        (A = gathered edge rows, B = dst vector replicated over 16 cols;
//         C gives lane the scores of edges kg*4+r -> exactly the PV A-frag
//         k-layout, so weights need no cross-lane movement).
// Softmax: log2-domain, deferred-max rescale (skip acc rescale unless the
//          tile max exceeds the running max by >8).
// PV: out += w^T . E via 4x mfma_f32_16x16x16f16 (K=16 edges, N=16 chans);
//     B-operand (E^T) staged through a wave-private LDS tile with layout
//     idx(e,c) = (c&15) + (e&3)*16 + (e>>2)*80 + (c>>4)*320:
//     writes = 2x ds_write_b128 (16B aligned), reads = 16x ds_read_u16,
//     read bank = (ql>>1) + 8j + 8*kg mod 32 -> conflict-free at fixed j.
//     Wave-private tile: same-wave DS ops execute in order, no barrier.
__global__ __launch_bounds__(256) void fused_node_kernel(const __half* __restrict__ fth,
                                                         const int* __restrict__ row_beg,
                                                         const int* __restrict__ row_end,
                                                         const int* __restrict__ edge_src,
                                                         float* __restrict__ out) {
    const float LOG2E = 1.44269504088896340736f;
    __shared__ _Float16 slds[4][1280];
    int wave = (blockIdx.x * 256 + threadIdx.x) >> 6;
    int lane = threadIdx.x & 63;
    if (wave >= N_NODES) return;
    _Float16* tile = slds[(threadIdx.x >> 6) & 3];
    int el = lane & 15, kg = lane >> 4;

    int beg = row_beg[wave];
    int end = row_end[wave];

    const _Float16* fh = (const _Float16*)fth;
    // B-frag for score MFMAs: d replicated over all 16 columns
    half8 db0 = *(const half8*)(fh + (size_t)wave * OUT_F + kg * 8);
    half8 db1 = *(const half8*)(fh + (size_t)wave * OUT_F + 32 + kg * 8);

    // LDS transpose addressing (halves)
    int widx = ((kg & 1) * 8) + (el & 3) * 16 + (el >> 2) * 80 + (kg >> 1) * 320;
    int ridx = el + 80 * kg;

    float m = -1e30f, l = 0.f;
    f32x4 accpv[4];
#pragma unroll
    for (int nb = 0; nb < 4; ++nb) accpv[nb] = (f32x4){0.f, 0.f, 0.f, 0.f};

    for (int i = beg; i < end; i += 16) {
        int e = i + el;
        int ce = (e < end) ? e : beg;            // clamp to a valid edge; masked below
        int es = edge_src[ce];
        half8 fa0 = *(const half8*)(fh + (size_t)es * OUT_F + kg * 8);
        half8 fa1 = *(const half8*)(fh + (size_t)es * OUT_F + 32 + kg * 8);
        // stage E^T tile for the PV B-operand
        *(half8*)(tile + widx) = fa0;
        *(half8*)(tile + widx + 640) = fa1;

        // scores: C[row=edge kg*4+r][col] (cols replicated)
        f32x4 sc2 = (f32x4){0.f, 0.f, 0.f, 0.f};
        sc2 = __builtin_amdgcn_mfma_f32_16x16x32_f16(fa0, db0, sc2, 0, 0, 0);
        sc2 = __builtin_amdgcn_mfma_f32_16x16x32_f16(fa1, db1, sc2, 0, 0, 0);

        int ebase = i + kg * 4;
        float p0 = (ebase + 0 < end) ? sc2[0] * LOG2E : -1e30f;
        float p1 = (ebase + 1 < end) ? sc2[1] * LOG2E : -1e30f;
        float p2 = (ebase + 2 < end) ? sc2[2] * LOG2E : -1e30f;
        float p3 = (ebase + 3 < end) ? sc2[3] * LOG2E : -1e30f;

        float pm = fmaxf(fmaxf(p0, p1), fmaxf(p2, p3));
        pm = fmaxf(pm, __shfl_xor(pm, 16));
        pm = fmaxf(pm, __shfl_xor(pm, 32));
        if (pm > m + 8.f) {                      // deferred-max rescale (T13)
            float alpha = exp2f(m - pm);
            l *= alpha;
#pragma unroll
            for (int nb = 0; nb < 4; ++nb) accpv[nb] *= alpha;
            m = pm;
        }
        float w0 = exp2f(p0 - m), w1 = exp2f(p1 - m);
        float w2 = exp2f(p2 - m), w3 = exp2f(p3 - m);
        l += (w0 + w1) + (w2 + w3);
        half4v wh = {(_Float16)w0, (_Float16)w1, (_Float16)w2, (_Float16)w3};

        __builtin_amdgcn_wave_barrier();
        // PV: A = w (rows replicated), B = E^T chunk from LDS
#pragma unroll
        for (int nb = 0; nb < 4; ++nb) {
            half4v bf;
#pragma unroll
            for (int j = 0; j < 4; ++j) bf[j] = tile[ridx + j * 16 + nb * 320];
            accpv[nb] = __builtin_amdgcn_mfma_f32_16x16x16f16(wh, bf, accpv[nb], 0, 0, 0);
        }
        __builtin_amdgcn_wave_barrier();
    }

    // l is per-kg partial (replicated over ql): reduce across kg only
    l += __shfl_xor(l, 16);
    l += __shfl_xor(l, 32);
    float inv = (l > 0.f) ? 1.f / l : 0.f;
    // PV C: col = ql = channel within chunk, rows replicated; lane stores
    // channel kg*16 + ql == lane  -> fully coalesced 256B row store
    float v = (kg == 0) ? accpv[0][0] : (kg == 1) ? accpv[1][0]
            : (kg == 2) ? accpv[2][0] : accpv[3][0];
    out[(size_t)wave * OUT_F + lane] = v * inv;
}

extern "C" void kernel_launch(void* const* d_in, const int* in_sizes, int n_in,
                              void* d_out, int out_size, void* d_ws, size_t ws_size,
                              hipStream_t stream) {
    const float* feat = (const float*)d_in[0];
    const float* W    = (const float*)d_in[1];
    const int*   src  = (const int*)d_in[2];
    const int*   dst  = (const int*)d_in[3];
    float* out = (float*)d_out;

    __half*   fth      = (__half*)d_ws;
    unsigned* staging  = (unsigned*)((int*)d_ws + (size_t)N_NODES * OUT_F / 2);
    int*      edge_src = (int*)(staging + (size_t)K_BKT * BKT_CAP);
    int*      bcursor  = edge_src + (size_t)K_BKT * BKT_CAP;
    int*      row_beg  = bcursor + K_BKT;
    int*      row_end  = row_beg + N_NODES;

    hipMemsetAsync(bcursor, 0, K_BKT * sizeof(int), stream);
    partition_linear_kernel<<<PBLKS + LBLKS, 256, 0, stream>>>(src, dst, bcursor, staging,
                                                               feat, W, fth);
    place_kernel<<<K_BKT, 256, 0, stream>>>(staging, bcursor, row_beg, row_end, edge_src);
    fused_node_kernel<<<(N_NODES * 64) / 256, 256, 0, stream>>>(fth, row_beg, row_end, edge_src, out);
}

// Round 3
// 204.966 us; speedup vs baseline: 1.0505x; 1.0505x over previous
//
#include <hip/hip_runtime.h>
#include <hip/hip_fp16.h>
#include <math.h>

#define N_NODES 100000
#define N_EDGES 1600000
#define IN_F    128
#define OUT_F   64
#define K_BKT     196                            // dst buckets of 512 nodes
#define BKT_SHIFT 9
#define BKT_NODES 512
#define BKT_CAP   10240                          // slots per bucket (E=8192, +22 sigma)
#define CHUNK     4096                           // partition block edge count
#define PBLKS     ((N_EDGES + CHUNK - 1) / CHUNK)          // 391
#define LTILES    (N_NODES / 16)                 // 6250 exact 16-row MFMA tiles
#define LBLKS     ((LTILES + 3) / 4)             // 1563 (4 waves/block)

typedef _Float16 half8 __attribute__((ext_vector_type(8)));
typedef float    f32x4 __attribute__((ext_vector_type(4)));

// ---------------- workspace layout (4-byte units) ----------------
// fth      : N_NODES*OUT_F/2       (fp16 projected features, 12.8 MB)
// staging  : K_BKT*BKT_CAP uint    (packed src|dloc<<17, capacity layout, 8 MB)
// edge_src : K_BKT*BKT_CAP int     (CSR src ids, capacity layout, 8 MB)
// bcursor  : K_BKT                 (zeroed by prep_kernel)
// row_beg/row_end : N_NODES each
// WT       : 64x128 fp16 (16 KB)   (W transposed, written by prep_kernel)

// 1 block: transpose W (128x64 f32) -> WT (64x128 fp16) + zero bcursor.
// Wave w handles k-rows [w*32, w*32+32), lane = column n. Reads coalesced
// (fixed k, consecutive n); each thread writes its own contiguous 64 B run.
__global__ __launch_bounds__(256) void prep_kernel(const float* __restrict__ W,
                                                   _Float16* __restrict__ WT,
                                                   int* __restrict__ bcursor) {
    int t = threadIdx.x;
    if (t < K_BKT) bcursor[t] = 0;
    int n = t & 63, kh = t >> 6;
    _Float16 tmp[32];
#pragma unroll
    for (int j = 0; j < 32; ++j)
        tmp[j] = (_Float16)W[(size_t)(kh * 32 + j) * OUT_F + n];
#pragma unroll
    for (int v = 0; v < 4; ++v)
        *(half8*)(WT + (size_t)n * IN_F + kh * 32 + v * 8) = *(half8*)&tmp[v * 8];
}

// blocks [0,PBLKS): in-LDS counting sort of a 4096-edge chunk into bucket
// regions at b*BKT_CAP (reservation atomics on 196 spread counters).
// blocks [PBLKS,..): MFMA fp16 linear — wave = 16-row tile of ft = feat @ W.
// B-fragments come from the pre-transposed fp16 WT: one half8 vector load
// per fragment (16/lane) instead of 128 stride-256B scalar f32 loads/lane
// (which pulled up to ~3.3 GB through L2 across 6250 waves).
__global__ __launch_bounds__(256) void partition_linear_kernel(const int* __restrict__ src,
                                                               const int* __restrict__ dst,
                                                               int* __restrict__ bcursor,
                                                               unsigned* __restrict__ staging,
                                                               const float* __restrict__ feat,
                                                               const _Float16* __restrict__ WT,
                                                               __half* __restrict__ fth) {
    __shared__ int hist[256], lbase[256], gbase[256], sc[256];
    __shared__ unsigned sval[CHUNK];
    __shared__ int spos[CHUNK];
    int t = threadIdx.x;
    if (blockIdx.x < PBLKS) {
        hist[t] = 0;
        __syncthreads();
        int beg = blockIdx.x * CHUNK;
        int end = min(beg + CHUNK, N_EDGES);
        for (int i = beg + t; i < end; i += 256)
            atomicAdd(&hist[dst[i] >> BKT_SHIFT], 1);
        __syncthreads();
        int v = hist[t];
        sc[t] = v;
        __syncthreads();
        for (int off = 1; off < 256; off <<= 1) {
            int add = (t >= off) ? sc[t - off] : 0;
            __syncthreads();
            sc[t] += add;
            __syncthreads();
        }
        lbase[t] = sc[t] - v;                    // block-local exclusive
        if (t < K_BKT && v) gbase[t] = t * BKT_CAP + atomicAdd(&bcursor[t], v);
        hist[t] = 0;                             // reuse as rank counter
        __syncthreads();
        for (int i = beg + t; i < end; i += 256) {
            int s = src[i], d = dst[i];
            int b = d >> BKT_SHIFT;
            int r = atomicAdd(&hist[b], 1);
            int lp = lbase[b] + r;
            sval[lp] = (unsigned)s | ((unsigned)(d & (BKT_NODES - 1)) << 17);
            spos[lp] = gbase[b] + r;
        }
        __syncthreads();
        int n = end - beg;
        for (int p = t; p < n; p += 256) staging[spos[p]] = sval[p];
        return;
    }
    // ---- MFMA linear: one wave per 16-row tile ----
    int gwave = (blockIdx.x - PBLKS) * 4 + (t >> 6);
    if (gwave >= LTILES) return;
    int lane = t & 63;
    int m = lane & 15, kg = lane >> 4;
    int r0 = gwave * 16;

    // B fragments from WT[n][k]: n = nb*16+m, k = kb*32 + kg*8 + j
    half8 fb[4][4];
#pragma unroll
    for (int kb = 0; kb < 4; ++kb)
#pragma unroll
        for (int nb = 0; nb < 4; ++nb)
            fb[kb][nb] = *(const half8*)(WT + (size_t)(nb * 16 + m) * IN_F + kb * 32 + kg * 8);

    f32x4 acc[4];
#pragma unroll
    for (int nb = 0; nb < 4; ++nb) acc[nb] = (f32x4){0.f, 0.f, 0.f, 0.f};

#pragma unroll
    for (int kb = 0; kb < 4; ++kb) {
        const float4* ap = (const float4*)(feat + (size_t)(r0 + m) * IN_F + kb * 32 + kg * 8);
        float4 a0 = ap[0], a1 = ap[1];
        half8 fa = {(_Float16)a0.x, (_Float16)a0.y, (_Float16)a0.z, (_Float16)a0.w,
                    (_Float16)a1.x, (_Float16)a1.y, (_Float16)a1.z, (_Float16)a1.w};
#pragma unroll
        for (int nb = 0; nb < 4; ++nb)
            acc[nb] = __builtin_amdgcn_mfma_f32_16x16x32_f16(fa, fb[kb][nb], acc[nb], 0, 0, 0);
    }
    // D: col = lane&15, row = (lane>>4)*4 + i
#pragma unroll
    for (int nb = 0; nb < 4; ++nb)
#pragma unroll
        for (int i = 0; i < 4; ++i)
            fth[(size_t)(r0 + kg * 4 + i) * OUT_F + nb * 16 + m] = __float2half_rn(acc[nb][i]);
}

// one block per bucket: per-node counts + scan -> row_beg/row_end, then place
// src ids into exact CSR slots (capacity layout). One block -> full lines.
__global__ __launch_bounds__(256) void place_kernel(const unsigned* __restrict__ staging,
                                                    const int* __restrict__ bcursor,
                                                    int* __restrict__ row_beg,
                                                    int* __restrict__ row_end,
                                                    int* __restrict__ edge_src) {
    __shared__ int cnt[BKT_NODES], sc[256], lcur[BKT_NODES];
    int t = threadIdx.x;
    cnt[t] = 0; cnt[t + 256] = 0;
    __syncthreads();
    int base = blockIdx.x * BKT_CAP;
    int n = bcursor[blockIdx.x];
    for (int i = t; i < n; i += 256)
        atomicAdd(&cnt[staging[base + i] >> 17], 1);
    __syncthreads();
    int v0 = cnt[2 * t], v1 = cnt[2 * t + 1];
    int ts = v0 + v1;
    sc[t] = ts;
    __syncthreads();
    for (int off = 1; off < 256; off <<= 1) {
        int add = (t >= off) ? sc[t - off] : 0;
        __syncthreads();
        sc[t] += add;
        __syncthreads();
    }
    int excl = sc[t] - ts;
    int node0 = blockIdx.x * BKT_NODES;
    int b0 = base + excl, b1 = base + excl + v0;
    lcur[2 * t]     = b0;
    lcur[2 * t + 1] = b1;
    if (node0 + 2 * t < N_NODES)     { row_beg[node0 + 2 * t] = b0;     row_end[node0 + 2 * t] = b0 + v0; }
    if (node0 + 2 * t + 1 < N_NODES) { row_beg[node0 + 2 * t + 1] = b1; row_end[node0 + 2 * t + 1] = b1 + v1; }
    __syncthreads();
    for (int i = base + t; i < base + n; i += 256) {
        unsigned u = staging[i];
        int pos = atomicAdd(&lcur[u >> 17], 1);
        edge_src[pos] = (int)(u & 0x1FFFFu);
    }
}

// one wave per dst node; 16 lanes/edge (4 fp16 channels/lane), 16 edges in
// flight (4 chains per quarter). Scores computed directly in log2 domain by
// pre-scaling the dst fragment with log2(e); one softmax rescale per 16
// edges. Invalid slots score -1e30 -> weight exp2()==0.
__global__ __launch_bounds__(256) void fused_node_kernel(const __half* __restrict__ fth,
                                                         const int* __restrict__ row_beg,
                                                         const int* __restrict__ row_end,
                                                         const int* __restrict__ edge_src,
                                                         float* __restrict__ out) {
    const float LOG2E = 1.44269504088896340736f;
    int wave = (blockIdx.x * 256 + threadIdx.x) >> 6;
    int lane = threadIdx.x & 63;
    if (wave >= N_NODES) return;
    int q = lane >> 4, ql = lane & 15;

    int beg = row_beg[wave];
    int end = row_end[wave];

    float2 rd = *(const float2*)(fth + (size_t)wave * OUT_F + 4 * ql);
    __half2 d01 = *(__half2*)&rd.x, d23 = *(__half2*)&rd.y;
    float fd0 = __half2float(d01.x) * LOG2E, fd1 = __half2float(d01.y) * LOG2E;
    float fd2 = __half2float(d23.x) * LOG2E, fd3 = __half2float(d23.y) * LOG2E;

    float m = -1e30f, l = 0.f;
    float a0 = 0.f, a1 = 0.f, a2 = 0.f, a3 = 0.f;

    for (int i = beg; i < end; i += 16) {
        int e0 = i + q, e1 = e0 + 4, e2 = e0 + 8, e3 = e0 + 12;
        bool u0 = e0 < end, u1 = e1 < end, u2 = e2 < end, u3 = e3 < end;
        int s0 = edge_src[u0 ? e0 : beg];
        int s1 = edge_src[u1 ? e1 : beg];
        int s2 = edge_src[u2 ? e2 : beg];
        int s3 = edge_src[u3 ? e3 : beg];
        float2 r0 = *(const float2*)(fth + (size_t)s0 * OUT_F + 4 * ql);
        float2 r1 = *(const float2*)(fth + (size_t)s1 * OUT_F + 4 * ql);
        float2 r2 = *(const float2*)(fth + (size_t)s2 * OUT_F + 4 * ql);
        float2 r3 = *(const float2*)(fth + (size_t)s3 * OUT_F + 4 * ql);
        __half2 A01 = *(__half2*)&r0.x, A23 = *(__half2*)&r0.y;
        __half2 B01 = *(__half2*)&r1.x, B23 = *(__half2*)&r1.y;
        __half2 C01 = *(__half2*)&r2.x, C23 = *(__half2*)&r2.y;
        __half2 D01 = *(__half2*)&r3.x, D23 = *(__half2*)&r3.y;
        float vA0 = __half2float(A01.x), vA1 = __half2float(A01.y);
        float vA2 = __half2float(A23.x), vA3 = __half2float(A23.y);
        float vB0 = __half2float(B01.x), vB1 = __half2float(B01.y);
        float vB2 = __half2float(B23.x), vB3 = __half2float(B23.y);
        float vC0 = __half2float(C01.x), vC1 = __half2float(C01.y);
        float vC2 = __half2float(C23.x), vC3 = __half2float(C23.y);
        float vD0 = __half2float(D01.x), vD1 = __half2float(D01.y);
        float vD2 = __half2float(D23.x), vD3 = __half2float(D23.y);

        float p0 = vA0 * fd0 + vA1 * fd1 + vA2 * fd2 + vA3 * fd3;
        float p1 = vB0 * fd0 + vB1 * fd1 + vB2 * fd2 + vB3 * fd3;
        float p2 = vC0 * fd0 + vC1 * fd1 + vC2 * fd2 + vC3 * fd3;
        float p3 = vD0 * fd0 + vD1 * fd1 + vD2 * fd2 + vD3 * fd3;
#pragma unroll
        for (int dd = 1; dd < 16; dd <<= 1) {
            p0 += __shfl_xor(p0, dd);
            p1 += __shfl_xor(p1, dd);
            p2 += __shfl_xor(p2, dd);
            p3 += __shfl_xor(p3, dd);
        }
        if (!u0) p0 = -1e30f;
        if (!u1) p1 = -1e30f;
        if (!u2) p2 = -1e30f;
        if (!u3) p3 = -1e30f;
        float nm = fmaxf(fmaxf(fmaxf(p0, p1), fmaxf(p2, p3)), m);
        float alpha = exp2f(m - nm);
        float w0 = exp2f(p0 - nm), w1 = exp2f(p1 - nm);
        float w2 = exp2f(p2 - nm), w3 = exp2f(p3 - nm);
        l = l * alpha + ((w0 + w1) + (w2 + w3));
        a0 = a0 * alpha + (w0 * vA0 + w1 * vB0) + (w2 * vC0 + w3 * vD0);
        a1 = a1 * alpha + (w0 * vA1 + w1 * vB1) + (w2 * vC1 + w3 * vD1);
        a2 = a2 * alpha + (w0 * vA2 + w1 * vB2) + (w2 * vC2 + w3 * vD2);
        a3 = a3 * alpha + (w0 * vA3 + w1 * vB3) + (w2 * vC3 + w3 * vD3);
        m = nm;
    }

    // merge the 4 quarter-states (xor16, then xor32) in log2 domain
#pragma unroll
    for (int dd = 16; dd <= 32; dd <<= 1) {
        float m2 = __shfl_xor(m, dd), l2 = __shfl_xor(l, dd);
        float b0 = __shfl_xor(a0, dd), b1 = __shfl_xor(a1, dd);
        float b2 = __shfl_xor(a2, dd), b3 = __shfl_xor(a3, dd);
        float M = fmaxf(m, m2);
        float e1 = exp2f(m - M), e2 = exp2f(m2 - M);
        l = l * e1 + l2 * e2;
        a0 = a0 * e1 + b0 * e2;
        a1 = a1 * e1 + b1 * e2;
        a2 = a2 * e1 + b2 * e2;
        a3 = a3 * e1 + b3 * e2;
        m = M;
    }
    if (q == 0) {
        float inv = (l > 0.f) ? 1.f / l : 0.f;
        *(float4*)(out + (size_t)wave * OUT_F + 4 * ql) =
            make_float4(a0 * inv, a1 * inv, a2 * inv, a3 * inv);
    }
}

extern "C" void kernel_launch(void* const* d_in, const int* in_sizes, int n_in,
                              void* d_out, int out_size, void* d_ws, size_t ws_size,
                              hipStream_t stream) {
    const float* feat = (const float*)d_in[0];
    const float* W    = (const float*)d_in[1];
    const int*   src  = (const int*)d_in[2];
    const int*   dst  = (const int*)d_in[3];
    float* out = (float*)d_out;

    __half*   fth      = (__half*)d_ws;
    unsigned* staging  = (unsigned*)((int*)d_ws + (size_t)N_NODES * OUT_F / 2);
    int*      edge_src = (int*)(staging + (size_t)K_BKT * BKT_CAP);
    int*      bcursor  = edge_src + (size_t)K_BKT * BKT_CAP;
    int*      row_beg  = bcursor + K_BKT;
    int*      row_end  = row_beg + N_NODES;
    _Float16* WT       = (_Float16*)(row_end + N_NODES);

    prep_kernel<<<1, 256, 0, stream>>>(W, WT, bcursor);
    partition_linear_kernel<<<PBLKS + LBLKS, 256, 0, stream>>>(src, dst, bcursor, staging,
                                                               feat, WT, fth);
    place_kernel<<<K_BKT, 256, 0, stream>>>(staging, bcursor, row_beg, row_end, edge_src);
    fused_node_kernel<<<(N_NODES * 64) / 256, 256, 0, stream>>>(fth, row_beg, row_end, edge_src, out);
}